// Round 4
// baseline (695.799 us; speedup 1.0000x reference)
//
#include <hip/hip_runtime.h>
#include <hip/hip_bf16.h>

// ShortTermInterestExtractor — GRU(64->64, T=200, B=4096) + attention + AUGRU.
// R3: R2 design (BT=8, 512 blocks = 2 blocks/CU; v_cvt_pk_bf16_f32 packing)
//     with the bit_cast compile error fixed via __builtin_memcpy.

#define Bq   4096
#define Tq   200
#define BT   8

typedef __attribute__((ext_vector_type(8))) short short8;  // 8 bf16 (4 VGPRs)
typedef __attribute__((ext_vector_type(4))) float f32x4;

#define MFMA(a, b, c) __builtin_amdgcn_mfma_f32_16x16x32_bf16((a), (b), (c), 0, 0, 0)

static __device__ __forceinline__ unsigned pk2(float a, float b) {
  __hip_bfloat162 t = __float22bfloat162_rn(make_float2(a, b));  // v_cvt_pk_bf16_f32
  unsigned r;
  __builtin_memcpy(&r, &t, sizeof(r));
  return r;
}
// Pack 4 fp32 -> bf16 hi (uint2) + bf16 lo (uint2), RNE, hi/lo split.
static __device__ __forceinline__ void pack4(f32x4 v, uint2 &H, uint2 &L) {
  H.x = pk2(v[0], v[1]);
  H.y = pk2(v[2], v[3]);
  float l0 = v[0] - __uint_as_float(H.x << 16);
  float l1 = v[1] - __uint_as_float(H.x & 0xffff0000u);
  float l2 = v[2] - __uint_as_float(H.y << 16);
  float l3 = v[3] - __uint_as_float(H.y & 0xffff0000u);
  L.x = pk2(l0, l1);
  L.y = pk2(l2, l3);
}
static __device__ __forceinline__ float sigm(float x) {
  return __builtin_amdgcn_rcpf(1.0f + __expf(-x));
}
static __device__ __forceinline__ float tanh_(float x) {
  return 2.0f * __builtin_amdgcn_rcpf(1.0f + __expf(-2.0f * x)) - 1.0f;
}
// Weight prologue split (not perf-critical).
static __device__ __forceinline__ void split8(f32x4 a, f32x4 b, short8 &hi, short8 &lo) {
  uint2 H, L;
  pack4(a, H, L);
  hi[0] = (short)(H.x & 0xffff); hi[1] = (short)(H.x >> 16);
  hi[2] = (short)(H.y & 0xffff); hi[3] = (short)(H.y >> 16);
  lo[0] = (short)(L.x & 0xffff); lo[1] = (short)(L.x >> 16);
  lo[2] = (short)(L.y & 0xffff); lo[3] = (short)(L.y >> 16);
  pack4(b, H, L);
  hi[4] = (short)(H.x & 0xffff); hi[5] = (short)(H.x >> 16);
  hi[6] = (short)(H.y & 0xffff); hi[7] = (short)(H.y >> 16);
  lo[4] = (short)(L.x & 0xffff); lo[5] = (short)(L.x >> 16);
  lo[6] = (short)(L.y & 0xffff); lo[7] = (short)(L.y >> 16);
}

// ---------------------------------------------------------------------------
// GRU + fused attention scores. 512 blocks x 256 thr (4 waves), 8 batch/block
// (MFMA cols 8..15 duplicate 0..7). Wave w owns hidden slice jh=16w.
// C layout (m89): col=lane&15 (=b), row=(lane>>4)*4+reg (=j).
// ---------------------------------------------------------------------------
__global__ __launch_bounds__(256, 2)
void gru_fwd(const float* __restrict__ x, const float* __restrict__ pq,
             const int* __restrict__ lengths,
             const float* __restrict__ Wih, const float* __restrict__ Whh,
             const float* __restrict__ bih, const float* __restrict__ bhh,
             unsigned short* __restrict__ outbf,   // [T][B][64] bf16
             float* __restrict__ scores)           // [B][T] fp32
{
  __shared__ alignas(16) unsigned short hbH[2][16][72], hbL[2][16][72];
  __shared__ alignas(16) unsigned short xbH[2][8][72], xbL[2][8][72];
  __shared__ float slds[2][4][8];

  const int tid  = threadIdx.x;
  const int w    = tid >> 6;
  const int lane = tid & 63;
  const int c    = lane & 15;        // MFMA col / h row
  const int g    = lane >> 4;        // k-octet / C row group
  const int jh   = w * 16;
  const int bl   = c & (BT - 1);
  const int b_g  = blockIdx.x * BT + bl;

  // x staging map: 8 b x 64 d fp32, 2 floats/thread
  const int pb   = tid >> 5;             // 0..7
  const int pd   = 2 * (tid & 31);       // 0..62
  const int pb_g = blockIdx.x * BT + pb;

  for (int i = tid; i < 16 * 72; i += 256) {
    hbH[0][0][i] = 0; hbL[0][0][i] = 0;
  }
  {  // stage x(t=0)
    float2 f = *(const float2*)(x + (size_t)pb_g * Tq * 64 + pd);
    unsigned H = pk2(f.x, f.y);
    float l0 = f.x - __uint_as_float(H << 16);
    float l1 = f.y - __uint_as_float(H & 0xffff0000u);
    *(unsigned*)&xbH[0][pb][pd] = H;
    *(unsigned*)&xbL[0][pb][pd] = pk2(l0, l1);
  }

  // Resident weight A-fragments (hi/lo): row m=c -> global row gate*64+jh+c.
  short8 wiH[3][2], wiL[3][2], whH[3][2], whL[3][2];
#pragma unroll
  for (int gt = 0; gt < 3; ++gt)
#pragma unroll
    for (int kc = 0; kc < 2; ++kc) {
      const float* p = Wih + (size_t)(gt * 64 + jh + c) * 64 + kc * 32 + g * 8;
      split8(*(const f32x4*)p, *(const f32x4*)(p + 4), wiH[gt][kc], wiL[gt][kc]);
      const float* q = Whh + (size_t)(gt * 64 + jh + c) * 64 + kc * 32 + g * 8;
      split8(*(const f32x4*)q, *(const f32x4*)(q + 4), whH[gt][kc], whL[gt][kc]);
    }

  f32x4 bR, bZ, bNi, bNh;
  {
    f32x4 bi0 = *(const f32x4*)(bih + 0 * 64 + jh + 4 * g);
    f32x4 bh0 = *(const f32x4*)(bhh + 0 * 64 + jh + 4 * g);
    f32x4 bi1 = *(const f32x4*)(bih + 1 * 64 + jh + 4 * g);
    f32x4 bh1 = *(const f32x4*)(bhh + 1 * 64 + jh + 4 * g);
    bR = bi0 + bh0; bZ = bi1 + bh1;
    bNi = *(const f32x4*)(bih + 2 * 64 + jh + 4 * g);
    bNh = *(const f32x4*)(bhh + 2 * 64 + jh + 4 * g);
  }
  const f32x4 pqv = *(const f32x4*)(pq + (size_t)b_g * 64 + jh + 4 * g);
  const int len = lengths[b_g];

  f32x4 hreg = {0.f, 0.f, 0.f, 0.f};
  __syncthreads();

  for (int t = 0; t < Tq; ++t) {
    const int cur = t & 1, nxt = cur ^ 1;

    // prefetch x(t+1) early
    float2 xf = make_float2(0.f, 0.f);
    if (t + 1 < Tq)
      xf = *(const float2*)(x + (size_t)pb_g * Tq * 64 + (size_t)(t + 1) * 64 + pd);

    short8 xH[2], xL[2], hH[2], hL[2];
#pragma unroll
    for (int kc = 0; kc < 2; ++kc) {
      xH[kc] = *(const short8*)&xbH[cur][bl][kc * 32 + g * 8];
      xL[kc] = *(const short8*)&xbL[cur][bl][kc * 32 + g * 8];
      hH[kc] = *(const short8*)&hbH[cur][c][kc * 32 + g * 8];
      hL[kc] = *(const short8*)&hbL[cur][c][kc * 32 + g * 8];
    }

    // finalize previous step's scores (wave 0)
    if (t > 0 && w == 0 && lane < BT) {
      float s = slds[nxt][0][lane] + slds[nxt][1][lane] +
                slds[nxt][2][lane] + slds[nxt][3][lane];
      scores[(size_t)(blockIdx.x * BT + lane) * Tq + (t - 1)] = s;
    }

    f32x4 aR = bR, aZ = bZ, aNi = bNi, aNh = bNh;
#pragma unroll
    for (int kc = 0; kc < 2; ++kc) {
      aR = MFMA(wiH[0][kc], xH[kc], aR);
      aR = MFMA(wiH[0][kc], xL[kc], aR);
      aR = MFMA(wiL[0][kc], xH[kc], aR);
      aR = MFMA(whH[0][kc], hH[kc], aR);
      aR = MFMA(whH[0][kc], hL[kc], aR);
      aR = MFMA(whL[0][kc], hH[kc], aR);
      aZ = MFMA(wiH[1][kc], xH[kc], aZ);
      aZ = MFMA(wiH[1][kc], xL[kc], aZ);
      aZ = MFMA(wiL[1][kc], xH[kc], aZ);
      aZ = MFMA(whH[1][kc], hH[kc], aZ);
      aZ = MFMA(whH[1][kc], hL[kc], aZ);
      aZ = MFMA(whL[1][kc], hH[kc], aZ);
      aNi = MFMA(wiH[2][kc], xH[kc], aNi);
      aNi = MFMA(wiH[2][kc], xL[kc], aNi);
      aNi = MFMA(wiL[2][kc], xH[kc], aNi);
      aNh = MFMA(whH[2][kc], hH[kc], aNh);
      aNh = MFMA(whH[2][kc], hL[kc], aNh);
      aNh = MFMA(whL[2][kc], hH[kc], aNh);
    }

    const bool valid = t < len;
    f32x4 outv;
#pragma unroll
    for (int r = 0; r < 4; ++r) {
      float rr = sigm(aR[r]);
      float zz = sigm(aZ[r]);
      float nn = tanh_(aNi[r] + rr * aNh[r]);
      float hn = (1.f - zz) * nn + zz * hreg[r];
      hreg[r] = valid ? hn : hreg[r];
      outv[r] = valid ? hn : 0.f;
    }

    // h (masked) -> LDS hi/lo for step t+1
    {
      uint2 H, L;
      pack4(hreg, H, L);
      *(uint2*)&hbH[nxt][c][jh + 4 * g] = H;
      *(uint2*)&hbL[nxt][c][jh + 4 * g] = L;
    }

    // attention score partial: dot(pq, out) over this lane's 4 j, reduce g.
    float sp = outv[0] * pqv[0] + outv[1] * pqv[1] + outv[2] * pqv[2] + outv[3] * pqv[3];
    sp += __shfl_xor(sp, 16);
    sp += __shfl_xor(sp, 32);
    if (lane < BT) slds[cur][w][lane] = sp;

    // out store (bf16) — only non-duplicate cols
    if (c < BT) {
      uint2 O;
      O.x = pk2(outv[0], outv[1]);
      O.y = pk2(outv[2], outv[3]);
      *(uint2*)(outbf + (size_t)t * Bq * 64 + (size_t)b_g * 64 + jh + 4 * g) = O;
    }

    // stage x(t+1)
    {
      unsigned H = pk2(xf.x, xf.y);
      float l0 = xf.x - __uint_as_float(H << 16);
      float l1 = xf.y - __uint_as_float(H & 0xffff0000u);
      *(unsigned*)&xbH[nxt][pb][pd] = H;
      *(unsigned*)&xbL[nxt][pb][pd] = pk2(l0, l1);
    }

    __syncthreads();
  }

  if (w == 0 && lane < BT) {
    const int pb2 = (Tq - 1) & 1;
    float s = slds[pb2][0][lane] + slds[pb2][1][lane] +
              slds[pb2][2][lane] + slds[pb2][3][lane];
    scores[(size_t)(blockIdx.x * BT + lane) * Tq + (Tq - 1)] = s;
  }
}

// ---------------------------------------------------------------------------
// Row softmax over scores (B rows of T=200). Wave per row.
// ---------------------------------------------------------------------------
__global__ __launch_bounds__(256)
void softmax_att(const float* __restrict__ scores, float* __restrict__ att)
{
  const int w = threadIdx.x >> 6, lane = threadIdx.x & 63;
  const int row = blockIdx.x * 4 + w;
  const float* s = scores + (size_t)row * Tq;
  float v0 = s[lane], v1 = s[lane + 64], v2 = s[lane + 128];
  float v3 = (lane < Tq - 192) ? s[lane + 192] : -1e30f;
  float m = fmaxf(fmaxf(v0, v1), fmaxf(v2, v3));
#pragma unroll
  for (int off = 32; off >= 1; off >>= 1) m = fmaxf(m, __shfl_xor(m, off));
  float e0 = __expf(v0 - m), e1 = __expf(v1 - m), e2 = __expf(v2 - m);
  float e3 = (lane < Tq - 192) ? __expf(v3 - m) : 0.f;
  float sum = e0 + e1 + e2 + e3;
#pragma unroll
  for (int off = 32; off >= 1; off >>= 1) sum += __shfl_xor(sum, off);
  float inv = 1.f / sum;
  float* a = att + (size_t)row * Tq;
  a[lane] = e0 * inv;
  a[lane + 64] = e1 * inv;
  a[lane + 128] = e2 * inv;
  if (lane < Tq - 192) a[lane + 192] = e3 * inv;
}

// ---------------------------------------------------------------------------
// AUGRU. Input = bf16 `out` read directly from global as B-frags (prefetched).
// ---------------------------------------------------------------------------
__global__ __launch_bounds__(256, 2)
void augru_fwd(const unsigned short* __restrict__ outbf, const float* __restrict__ att,
               const int* __restrict__ lengths,
               const float* __restrict__ Wih, const float* __restrict__ Whh,
               const float* __restrict__ bih, const float* __restrict__ bhh,
               float* __restrict__ hout)
{
  __shared__ alignas(16) unsigned short hbH[2][16][72], hbL[2][16][72];
  __shared__ float att_lds[BT][204];

  const int tid  = threadIdx.x;
  const int w    = tid >> 6;
  const int lane = tid & 63;
  const int c    = lane & 15;
  const int g    = lane >> 4;
  const int jh   = w * 16;
  const int bl   = c & (BT - 1);
  const int b_g  = blockIdx.x * BT + bl;

  for (int i = tid; i < 16 * 72; i += 256) {
    hbH[0][0][i] = 0; hbL[0][0][i] = 0;
  }
  for (int i = tid; i < BT * Tq; i += 256)
    att_lds[i / Tq][i % Tq] = att[(size_t)blockIdx.x * BT * Tq + i];

  short8 wiH[3][2], wiL[3][2], whH[3][2], whL[3][2];
#pragma unroll
  for (int gt = 0; gt < 3; ++gt)
#pragma unroll
    for (int kc = 0; kc < 2; ++kc) {
      const float* p = Wih + (size_t)(gt * 64 + jh + c) * 64 + kc * 32 + g * 8;
      split8(*(const f32x4*)p, *(const f32x4*)(p + 4), wiH[gt][kc], wiL[gt][kc]);
      const float* q = Whh + (size_t)(gt * 64 + jh + c) * 64 + kc * 32 + g * 8;
      split8(*(const f32x4*)q, *(const f32x4*)(q + 4), whH[gt][kc], whL[gt][kc]);
    }

  f32x4 bR, bZ, bNi, bNh;
  {
    f32x4 bi0 = *(const f32x4*)(bih + 0 * 64 + jh + 4 * g);
    f32x4 bh0 = *(const f32x4*)(bhh + 0 * 64 + jh + 4 * g);
    f32x4 bi1 = *(const f32x4*)(bih + 1 * 64 + jh + 4 * g);
    f32x4 bh1 = *(const f32x4*)(bhh + 1 * 64 + jh + 4 * g);
    bR = bi0 + bh0; bZ = bi1 + bh1;
    bNi = *(const f32x4*)(bih + 2 * 64 + jh + 4 * g);
    bNh = *(const f32x4*)(bhh + 2 * 64 + jh + 4 * g);
  }
  const int len = lengths[b_g];

  short8 xcur[2];
#pragma unroll
  for (int kc = 0; kc < 2; ++kc)
    xcur[kc] = *(const short8*)(outbf + (size_t)b_g * 64 + kc * 32 + g * 8);

  f32x4 hreg = {0.f, 0.f, 0.f, 0.f};
  __syncthreads();

  for (int t = 0; t < Tq; ++t) {
    const int cur = t & 1, nxt = cur ^ 1;

    short8 xnxt[2];
    if (t + 1 < Tq) {
#pragma unroll
      for (int kc = 0; kc < 2; ++kc)
        xnxt[kc] = *(const short8*)(outbf + (size_t)(t + 1) * Bq * 64 +
                                    (size_t)b_g * 64 + kc * 32 + g * 8);
    } else {
      xnxt[0] = xcur[0]; xnxt[1] = xcur[1];
    }

    short8 hH[2], hL[2];
#pragma unroll
    for (int kc = 0; kc < 2; ++kc) {
      hH[kc] = *(const short8*)&hbH[cur][c][kc * 32 + g * 8];
      hL[kc] = *(const short8*)&hbL[cur][c][kc * 32 + g * 8];
    }
    const float a_t = att_lds[bl][t];

    f32x4 aR = bR, aZ = bZ, aNi = bNi, aNh = bNh;
#pragma unroll
    for (int kc = 0; kc < 2; ++kc) {
      aR = MFMA(wiH[0][kc], xcur[kc], aR);
      aR = MFMA(wiL[0][kc], xcur[kc], aR);
      aR = MFMA(whH[0][kc], hH[kc], aR);
      aR = MFMA(whH[0][kc], hL[kc], aR);
      aR = MFMA(whL[0][kc], hH[kc], aR);
      aZ = MFMA(wiH[1][kc], xcur[kc], aZ);
      aZ = MFMA(wiL[1][kc], xcur[kc], aZ);
      aZ = MFMA(whH[1][kc], hH[kc], aZ);
      aZ = MFMA(whH[1][kc], hL[kc], aZ);
      aZ = MFMA(whL[1][kc], hH[kc], aZ);
      aNi = MFMA(wiH[2][kc], xcur[kc], aNi);
      aNi = MFMA(wiL[2][kc], xcur[kc], aNi);
      aNh = MFMA(whH[2][kc], hH[kc], aNh);
      aNh = MFMA(whH[2][kc], hL[kc], aNh);
      aNh = MFMA(whL[2][kc], hH[kc], aNh);
    }

    const bool valid = t < len;
#pragma unroll
    for (int r = 0; r < 4; ++r) {
      float rr = sigm(aR[r]);
      float uu = a_t * sigm(aZ[r]);
      float nn = tanh_(aNi[r] + rr * aNh[r]);
      float hn = (1.f - uu) * hreg[r] + uu * nn;   // AUGRU blend orientation
      hreg[r] = valid ? hn : hreg[r];
    }

    {
      uint2 H, L;
      pack4(hreg, H, L);
      *(uint2*)&hbH[nxt][c][jh + 4 * g] = H;
      *(uint2*)&hbL[nxt][c][jh + 4 * g] = L;
    }

    xcur[0] = xnxt[0]; xcur[1] = xnxt[1];
    __syncthreads();
  }

  if (c < BT)
    *(f32x4*)(hout + (size_t)b_g * 64 + jh + 4 * g) = hreg;
}

// ---------------------------------------------------------------------------
extern "C" void kernel_launch(void* const* d_in, const int* in_sizes, int n_in,
                              void* d_out, int out_size, void* d_ws, size_t ws_size,
                              hipStream_t stream)
{
  const float* x       = (const float*)d_in[0];
  const float* pq      = (const float*)d_in[1];
  const int*   lengths = (const int*)d_in[2];
  const float* Wih     = (const float*)d_in[3];
  const float* Whh     = (const float*)d_in[4];
  const float* bih     = (const float*)d_in[5];
  const float* bhh     = (const float*)d_in[6];
  const float* aWih    = (const float*)d_in[7];
  const float* aWhh    = (const float*)d_in[8];
  const float* abih    = (const float*)d_in[9];
  const float* abhh    = (const float*)d_in[10];
  float* hout = (float*)d_out;

  // ws: out bf16 [T][B][64] (104.8 MB) | scores [B][T] | att [B][T]
  char* ws = (char*)d_ws;
  unsigned short* outbf = (unsigned short*)ws;
  float* scores = (float*)(ws + (size_t)Tq * Bq * 64 * 2);
  float* att    = scores + (size_t)Bq * Tq;

  gru_fwd<<<Bq / BT, 256, 0, stream>>>(x, pq, lengths, Wih, Whh, bih, bhh, outbf, scores);
  softmax_att<<<Bq / 4, 256, 0, stream>>>(scores, att);
  augru_fwd<<<Bq / BT, 256, 0, stream>>>(outbf, att, lengths, aWih, aWhh, abih, abhh, hout);
}

// Round 5
// 598.204 us; speedup vs baseline: 1.1631x; 1.1631x over previous
//
#include <hip/hip_runtime.h>
#include <hip/hip_bf16.h>

// ShortTermInterestExtractor — GRU(64->64, T=200, B=4096) + attention + AUGRU.
// R5: BT=16 (R1 shape) + (1) lgkm-only per-step barrier (no vmcnt drain),
//     (2) software-pipelined gi = W_ih·x (next step's input GEMM overlaps this
//     step's gate VALU; gh accumulates into precomputed gi), (3) XOR-swizzled
//     LDS tiles (byte ^= (row&7)<<4) to kill 8-way frag-read bank conflicts.

#define Bq   4096
#define Tq   200
#define BT   16

typedef __attribute__((ext_vector_type(8))) short short8;  // 8 bf16 (4 VGPRs)
typedef __attribute__((ext_vector_type(4))) float f32x4;

#define MFMA(a, b, c) __builtin_amdgcn_mfma_f32_16x16x32_bf16((a), (b), (c), 0, 0, 0)

// lgkm-only barrier: LDS producer/consumer sync without draining vmcnt
// (global stores/prefetches stay in flight across steps).
#define LGKM_BARRIER()                                      \
  do {                                                      \
    __builtin_amdgcn_sched_barrier(0);                      \
    asm volatile("s_waitcnt lgkmcnt(0)" ::: "memory");      \
    __builtin_amdgcn_s_barrier();                           \
    asm volatile("" ::: "memory");                          \
    __builtin_amdgcn_sched_barrier(0);                      \
  } while (0)

// Swizzled short-index into a [16][64]-short tile (128B rows):
// byte = (colshort*2) ^ ((row&7)<<4). All accesses are 8B/16B chunks inside a
// 16B block, so the XOR (bits>=4) is consistent between writers and readers.
static __device__ __forceinline__ int swz(int row, int colshort) {
  return row * 64 + ((((colshort) << 1) ^ ((row & 7) << 4)) >> 1);
}

static __device__ __forceinline__ unsigned pk2(float a, float b) {
  __hip_bfloat162 t = __float22bfloat162_rn(make_float2(a, b));  // v_cvt_pk_bf16_f32
  unsigned r;
  __builtin_memcpy(&r, &t, sizeof(r));
  return r;
}
// Pack 4 fp32 -> bf16 hi (uint2) + bf16 lo (uint2), RNE hi/lo split.
static __device__ __forceinline__ void pack4(f32x4 v, uint2 &H, uint2 &L) {
  H.x = pk2(v[0], v[1]);
  H.y = pk2(v[2], v[3]);
  float l0 = v[0] - __uint_as_float(H.x << 16);
  float l1 = v[1] - __uint_as_float(H.x & 0xffff0000u);
  float l2 = v[2] - __uint_as_float(H.y << 16);
  float l3 = v[3] - __uint_as_float(H.y & 0xffff0000u);
  L.x = pk2(l0, l1);
  L.y = pk2(l2, l3);
}
static __device__ __forceinline__ float sigm(float x) {
  return __builtin_amdgcn_rcpf(1.0f + __expf(-x));
}
static __device__ __forceinline__ float tanh_(float x) {
  return 2.0f * __builtin_amdgcn_rcpf(1.0f + __expf(-2.0f * x)) - 1.0f;
}
// Weight prologue split (not perf-critical).
static __device__ __forceinline__ void split8(f32x4 a, f32x4 b, short8 &hi, short8 &lo) {
  uint2 H, L;
  pack4(a, H, L);
  hi[0] = (short)(H.x & 0xffff); hi[1] = (short)(H.x >> 16);
  hi[2] = (short)(H.y & 0xffff); hi[3] = (short)(H.y >> 16);
  lo[0] = (short)(L.x & 0xffff); lo[1] = (short)(L.x >> 16);
  lo[2] = (short)(L.y & 0xffff); lo[3] = (short)(L.y >> 16);
  pack4(b, H, L);
  hi[4] = (short)(H.x & 0xffff); hi[5] = (short)(H.x >> 16);
  hi[6] = (short)(H.y & 0xffff); hi[7] = (short)(H.y >> 16);
  lo[4] = (short)(L.x & 0xffff); lo[5] = (short)(L.x >> 16);
  lo[6] = (short)(L.y & 0xffff); lo[7] = (short)(L.y >> 16);
}

// 18 MFMAs: 3-term hi/lo input GEMM (weights wi, activations XH/XL).
#define GI_X18(dR, dZ, dN, XH, XL)                   \
  _Pragma("unroll")                                  \
  for (int kc = 0; kc < 2; ++kc) {                   \
    dR = MFMA(wiH[0][kc], XH[kc], dR);               \
    dR = MFMA(wiH[0][kc], XL[kc], dR);               \
    dR = MFMA(wiL[0][kc], XH[kc], dR);               \
    dZ = MFMA(wiH[1][kc], XH[kc], dZ);               \
    dZ = MFMA(wiH[1][kc], XL[kc], dZ);               \
    dZ = MFMA(wiL[1][kc], XH[kc], dZ);               \
    dN = MFMA(wiH[2][kc], XH[kc], dN);               \
    dN = MFMA(wiH[2][kc], XL[kc], dN);               \
    dN = MFMA(wiL[2][kc], XH[kc], dN);               \
  }

// 12 MFMAs: 2-term (bf16 input) GEMM for AUGRU's input side.
#define GI_X12(dR, dZ, dN, XB)                       \
  _Pragma("unroll")                                  \
  for (int kc = 0; kc < 2; ++kc) {                   \
    dR = MFMA(wiH[0][kc], XB[kc], dR);               \
    dR = MFMA(wiL[0][kc], XB[kc], dR);               \
    dZ = MFMA(wiH[1][kc], XB[kc], dZ);               \
    dZ = MFMA(wiL[1][kc], XB[kc], dZ);               \
    dN = MFMA(wiH[2][kc], XB[kc], dN);               \
    dN = MFMA(wiL[2][kc], XB[kc], dN);               \
  }

// 18 MFMAs: hidden GEMM; R/Z accumulate into precomputed gi, N into aNh.
#define GH18(dR, dZ, dNh)                            \
  _Pragma("unroll")                                  \
  for (int kc = 0; kc < 2; ++kc) {                   \
    dR  = MFMA(whH[0][kc], hH[kc], dR);              \
    dR  = MFMA(whH[0][kc], hL[kc], dR);              \
    dR  = MFMA(whL[0][kc], hH[kc], dR);              \
    dZ  = MFMA(whH[1][kc], hH[kc], dZ);              \
    dZ  = MFMA(whH[1][kc], hL[kc], dZ);              \
    dZ  = MFMA(whL[1][kc], hH[kc], dZ);              \
    dNh = MFMA(whH[2][kc], hH[kc], dNh);             \
    dNh = MFMA(whH[2][kc], hL[kc], dNh);             \
    dNh = MFMA(whL[2][kc], hH[kc], dNh);             \
  }

#define LOAD_WEIGHTS(WI, WH)                                                  \
  _Pragma("unroll")                                                           \
  for (int gt = 0; gt < 3; ++gt)                                              \
  _Pragma("unroll")                                                           \
    for (int kc = 0; kc < 2; ++kc) {                                          \
      const float* p = WI + (size_t)(gt * 64 + jh + c) * 64 + kc * 32 + g * 8;\
      split8(*(const f32x4*)p, *(const f32x4*)(p + 4), wiH[gt][kc], wiL[gt][kc]); \
      const float* q = WH + (size_t)(gt * 64 + jh + c) * 64 + kc * 32 + g * 8;\
      split8(*(const f32x4*)q, *(const f32x4*)(q + 4), whH[gt][kc], whL[gt][kc]); \
    }

#define LOAD_BIASES(BI, BH)                                                   \
  {                                                                           \
    f32x4 bi0 = *(const f32x4*)(BI + 0 * 64 + jh + 4 * g);                    \
    f32x4 bh0 = *(const f32x4*)(BH + 0 * 64 + jh + 4 * g);                    \
    f32x4 bi1 = *(const f32x4*)(BI + 1 * 64 + jh + 4 * g);                    \
    f32x4 bh1 = *(const f32x4*)(BH + 1 * 64 + jh + 4 * g);                    \
    bR = bi0 + bh0; bZ = bi1 + bh1;                                           \
    bNi = *(const f32x4*)(BI + 2 * 64 + jh + 4 * g);                          \
    bNh = *(const f32x4*)(BH + 2 * 64 + jh + 4 * g);                          \
  }

// ---------------------------------------------------------------------------
// GRU + fused attention scores. 256 blocks x 256 thr (4 waves), 16 batch/blk.
// Wave w owns hidden slice jh=16w. C layout (m89): col=lane&15 (=b),
// row=(lane>>4)*4+reg (=j). A/B frags: 16-dim = lane&15, k = (lane>>4)*8+e.
// ---------------------------------------------------------------------------
__global__ __launch_bounds__(256, 1)
void gru_fwd(const float* __restrict__ x, const float* __restrict__ pq,
             const int* __restrict__ lengths,
             const float* __restrict__ Wih, const float* __restrict__ Whh,
             const float* __restrict__ bih, const float* __restrict__ bhh,
             unsigned short* __restrict__ outbf,   // [T][B][64] bf16
             float* __restrict__ scores)           // [B][T] fp32
{
  __shared__ alignas(16) unsigned short hbH[2][1024], hbL[2][1024];
  __shared__ alignas(16) unsigned short xbH[2][1024], xbL[2][1024];
  __shared__ float slds[2][4][16];

  const int tid  = threadIdx.x;
  const int w    = tid >> 6;
  const int lane = tid & 63;
  const int c    = lane & 15;        // batch col / A row
  const int g    = lane >> 4;        // k-octet / C row group
  const int jh   = w * 16;
  const int b_g  = blockIdx.x * BT + c;

  // x staging map: 16 b x 64 d fp32, 4 floats/thread
  const int pb   = tid >> 4;
  const int pd   = 4 * (tid & 15);
  const int pb_g = blockIdx.x * BT + pb;

  for (int i = tid; i < 1024; i += 256) { hbH[0][i] = 0; hbL[0][i] = 0; }

  // stage x(0), x(1)
#pragma unroll
  for (int t0 = 0; t0 < 2; ++t0) {
    f32x4 xf = *(const f32x4*)(x + (size_t)pb_g * Tq * 64 + t0 * 64 + pd);
    uint2 H, L; pack4(xf, H, L);
    const int si = swz(pb, pd);
    *(uint2*)&xbH[t0][si] = H;
    *(uint2*)&xbL[t0][si] = L;
  }

  short8 wiH[3][2], wiL[3][2], whH[3][2], whL[3][2];
  LOAD_WEIGHTS(Wih, Whh);
  f32x4 bR, bZ, bNi, bNh;
  LOAD_BIASES(bih, bhh);
  const f32x4 pqv = *(const f32x4*)(pq + (size_t)b_g * 64 + jh + 4 * g);
  const int len = lengths[b_g];

  __syncthreads();

  // gi(0) from xb[0]
  f32x4 giR = bR, giZ = bZ, giN = bNi;
  {
    short8 xH[2], xL[2];
#pragma unroll
    for (int kc = 0; kc < 2; ++kc) {
      const int si = swz(c, kc * 32 + g * 8);
      xH[kc] = *(const short8*)&xbH[0][si];
      xL[kc] = *(const short8*)&xbL[0][si];
    }
    GI_X18(giR, giZ, giN, xH, xL);
  }

  f32x4 hreg = {0.f, 0.f, 0.f, 0.f};

  for (int t = 0; t < Tq; ++t) {
    const int cur = t & 1, nxt = cur ^ 1;
    const bool more = (t + 1 < Tq);

    // global prefetch x(t+2)
    f32x4 xf = {0.f, 0.f, 0.f, 0.f};
    if (t + 2 < Tq)
      xf = *(const f32x4*)(x + (size_t)pb_g * Tq * 64 + (size_t)(t + 2) * 64 + pd);

    // h(t) frags from hb[cur]; x(t+1) frags from xb[nxt]
    short8 hH[2], hL[2], xnH[2], xnL[2];
#pragma unroll
    for (int kc = 0; kc < 2; ++kc) {
      const int si = swz(c, kc * 32 + g * 8);
      hH[kc] = *(const short8*)&hbH[cur][si];
      hL[kc] = *(const short8*)&hbL[cur][si];
    }
    if (more) {
#pragma unroll
      for (int kc = 0; kc < 2; ++kc) {
        const int si = swz(c, kc * 32 + g * 8);
        xnH[kc] = *(const short8*)&xbH[nxt][si];
        xnL[kc] = *(const short8*)&xbL[nxt][si];
      }
    }

    // finalize previous step's scores (wave 0)
    if (t > 0 && w == 0 && lane < 16) {
      float s = slds[nxt][0][lane] + slds[nxt][1][lane] +
                slds[nxt][2][lane] + slds[nxt][3][lane];
      scores[(size_t)(blockIdx.x * BT + lane) * Tq + (t - 1)] = s;
    }

    // hidden GEMM accumulates into precomputed gi (R,Z) and aNh (N)
    f32x4 aNh = bNh;
    GH18(giR, giZ, aNh);

    const bool valid = t < len;
    f32x4 outv;
#pragma unroll
    for (int r = 0; r < 4; ++r) {
      float rr = sigm(giR[r]);
      float zz = sigm(giZ[r]);
      float nn = tanh_(giN[r] + rr * aNh[r]);
      float hn = (1.f - zz) * nn + zz * hreg[r];
      hreg[r] = valid ? hn : hreg[r];
      outv[r] = valid ? hn : 0.f;
    }

    // h (masked) -> LDS hi/lo for step t+1
    {
      uint2 H, L;
      pack4(hreg, H, L);
      const int si = swz(c, jh + 4 * g);
      *(uint2*)&hbH[nxt][si] = H;
      *(uint2*)&hbL[nxt][si] = L;
    }

    // attention score partial: dot(pq, out) over this lane's 4 j, reduce g+w.
    float sp = outv[0] * pqv[0] + outv[1] * pqv[1] + outv[2] * pqv[2] + outv[3] * pqv[3];
    sp += __shfl_xor(sp, 16);
    sp += __shfl_xor(sp, 32);
    if (lane < 16) slds[cur][w][lane] = sp;

    // out store (bf16)
    {
      uint2 O;
      O.x = pk2(outv[0], outv[1]);
      O.y = pk2(outv[2], outv[3]);
      *(uint2*)(outbf + (size_t)t * Bq * 64 + (size_t)b_g * 64 + jh + 4 * g) = O;
    }

    // gi(t+1): overlaps the gate VALU above on the MFMA pipe
    f32x4 nR = bR, nZ = bZ, nN = bNi;
    if (more) { GI_X18(nR, nZ, nN, xnH, xnL); }

    // stage x(t+2) into xb[cur]
    if (t + 2 < Tq) {
      uint2 H, L; pack4(xf, H, L);
      const int si = swz(pb, pd);
      *(uint2*)&xbH[cur][si] = H;
      *(uint2*)&xbL[cur][si] = L;
    }

    LGKM_BARRIER();
    giR = nR; giZ = nZ; giN = nN;
  }

  if (w == 0 && lane < 16) {
    const int pb2 = (Tq - 1) & 1;
    float s = slds[pb2][0][lane] + slds[pb2][1][lane] +
              slds[pb2][2][lane] + slds[pb2][3][lane];
    scores[(size_t)(blockIdx.x * BT + lane) * Tq + (Tq - 1)] = s;
  }
}

// ---------------------------------------------------------------------------
// Row softmax over scores (B rows of T=200). Wave per row.
// ---------------------------------------------------------------------------
__global__ __launch_bounds__(256)
void softmax_att(const float* __restrict__ scores, float* __restrict__ att)
{
  const int w = threadIdx.x >> 6, lane = threadIdx.x & 63;
  const int row = blockIdx.x * 4 + w;
  const float* s = scores + (size_t)row * Tq;
  float v0 = s[lane], v1 = s[lane + 64], v2 = s[lane + 128];
  float v3 = (lane < Tq - 192) ? s[lane + 192] : -1e30f;
  float m = fmaxf(fmaxf(v0, v1), fmaxf(v2, v3));
#pragma unroll
  for (int off = 32; off >= 1; off >>= 1) m = fmaxf(m, __shfl_xor(m, off));
  float e0 = __expf(v0 - m), e1 = __expf(v1 - m), e2 = __expf(v2 - m);
  float e3 = (lane < Tq - 192) ? __expf(v3 - m) : 0.f;
  float sum = e0 + e1 + e2 + e3;
#pragma unroll
  for (int off = 32; off >= 1; off >>= 1) sum += __shfl_xor(sum, off);
  float inv = 1.f / sum;
  float* a = att + (size_t)row * Tq;
  a[lane] = e0 * inv;
  a[lane + 64] = e1 * inv;
  a[lane + 128] = e2 * inv;
  if (lane < Tq - 192) a[lane + 192] = e3 * inv;
}

// ---------------------------------------------------------------------------
// AUGRU. Input = bf16 `out` read directly from global as B-frags; gi(t+1)
// pipelined the same way (12 MFMAs, input already bf16 so no lo term).
// ---------------------------------------------------------------------------
__global__ __launch_bounds__(256, 1)
void augru_fwd(const unsigned short* __restrict__ outbf, const float* __restrict__ att,
               const int* __restrict__ lengths,
               const float* __restrict__ Wih, const float* __restrict__ Whh,
               const float* __restrict__ bih, const float* __restrict__ bhh,
               float* __restrict__ hout)
{
  __shared__ alignas(16) unsigned short hbH[2][1024], hbL[2][1024];
  __shared__ float att_lds[16][201];   // 201 stride: 16 rows -> 16 distinct banks

  const int tid  = threadIdx.x;
  const int w    = tid >> 6;
  const int lane = tid & 63;
  const int c    = lane & 15;
  const int g    = lane >> 4;
  const int jh   = w * 16;
  const int b_g  = blockIdx.x * BT + c;

  for (int i = tid; i < 1024; i += 256) { hbH[0][i] = 0; hbL[0][i] = 0; }
  for (int i = tid; i < BT * Tq; i += 256)
    att_lds[i / Tq][i % Tq] = att[(size_t)blockIdx.x * BT * Tq + i];

  short8 wiH[3][2], wiL[3][2], whH[3][2], whL[3][2];
  LOAD_WEIGHTS(Wih, Whh);
  f32x4 bR, bZ, bNi, bNh;
  LOAD_BIASES(bih, bhh);
  const int len = lengths[b_g];

  // gi(0) from out(0) global frags
  f32x4 giR = bR, giZ = bZ, giN = bNi;
  {
    short8 x0[2];
#pragma unroll
    for (int kc = 0; kc < 2; ++kc)
      x0[kc] = *(const short8*)(outbf + (size_t)b_g * 64 + kc * 32 + g * 8);
    GI_X12(giR, giZ, giN, x0);
  }

  f32x4 hreg = {0.f, 0.f, 0.f, 0.f};
  __syncthreads();

  for (int t = 0; t < Tq; ++t) {
    const int cur = t & 1, nxt = cur ^ 1;
    const bool more = (t + 1 < Tq);

    // out(t+1) frags direct from global (consumed at step end -> latency hidden)
    short8 xn[2];
    if (more) {
#pragma unroll
      for (int kc = 0; kc < 2; ++kc)
        xn[kc] = *(const short8*)(outbf + (size_t)(t + 1) * Bq * 64 +
                                  (size_t)b_g * 64 + kc * 32 + g * 8);
    }

    short8 hH[2], hL[2];
#pragma unroll
    for (int kc = 0; kc < 2; ++kc) {
      const int si = swz(c, kc * 32 + g * 8);
      hH[kc] = *(const short8*)&hbH[cur][si];
      hL[kc] = *(const short8*)&hbL[cur][si];
    }
    const float a_t = att_lds[c][t];

    f32x4 aNh = bNh;
    GH18(giR, giZ, aNh);

    const bool valid = t < len;
#pragma unroll
    for (int r = 0; r < 4; ++r) {
      float rr = sigm(giR[r]);
      float uu = a_t * sigm(giZ[r]);
      float nn = tanh_(giN[r] + rr * aNh[r]);
      float hn = (1.f - uu) * hreg[r] + uu * nn;   // AUGRU blend orientation
      hreg[r] = valid ? hn : hreg[r];
    }

    {
      uint2 H, L;
      pack4(hreg, H, L);
      const int si = swz(c, jh + 4 * g);
      *(uint2*)&hbH[nxt][si] = H;
      *(uint2*)&hbL[nxt][si] = L;
    }

    // gi(t+1) pipelined
    f32x4 nR = bR, nZ = bZ, nN = bNi;
    if (more) { GI_X12(nR, nZ, nN, xn); }

    LGKM_BARRIER();
    giR = nR; giZ = nZ; giN = nN;
  }

  *(f32x4*)(hout + (size_t)b_g * 64 + jh + 4 * g) = hreg;
}

// ---------------------------------------------------------------------------
extern "C" void kernel_launch(void* const* d_in, const int* in_sizes, int n_in,
                              void* d_out, int out_size, void* d_ws, size_t ws_size,
                              hipStream_t stream)
{
  const float* x       = (const float*)d_in[0];
  const float* pq      = (const float*)d_in[1];
  const int*   lengths = (const int*)d_in[2];
  const float* Wih     = (const float*)d_in[3];
  const float* Whh     = (const float*)d_in[4];
  const float* bih     = (const float*)d_in[5];
  const float* bhh     = (const float*)d_in[6];
  const float* aWih    = (const float*)d_in[7];
  const float* aWhh    = (const float*)d_in[8];
  const float* abih    = (const float*)d_in[9];
  const float* abhh    = (const float*)d_in[10];
  float* hout = (float*)d_out;

  // ws: out bf16 [T][B][64] (104.8 MB) | scores [B][T] | att [B][T]
  char* ws = (char*)d_ws;
  unsigned short* outbf = (unsigned short*)ws;
  float* scores = (float*)(ws + (size_t)Tq * Bq * 64 * 2);
  float* att    = scores + (size_t)Bq * Tq;

  gru_fwd<<<Bq / BT, 256, 0, stream>>>(x, pq, lengths, Wih, Whh, bih, bhh, outbf, scores);
  softmax_att<<<Bq / 4, 256, 0, stream>>>(scores, att);
  augru_fwd<<<Bq / BT, 256, 0, stream>>>(outbf, att, lengths, aWih, aWhh, abih, abhh, hout);
}

// Round 7
// 583.446 us; speedup vs baseline: 1.1926x; 1.0253x over previous
//
#include <hip/hip_runtime.h>
#include <hip/hip_bf16.h>

// ShortTermInterestExtractor — GRU(64->64, T=200, B=4096) + attention + AUGRU.
// R6: wave specialization. 512-thr blocks = 8 waves: waves 0-3 "critical"
// (h-recurrence: GH18 + gates + h LDS exchange), waves 4-7 "helper"
// (x staging/convert, gi = W_ih·x for t+1 via LDS handoff, score finalize).
// 256 blocks x 8 waves = 2048 waves = 2 waves/SIMD with no duplicated work.

#define Bq   4096
#define Tq   200
#define BT   16

typedef __attribute__((ext_vector_type(8))) short short8;  // 8 bf16 (4 VGPRs)
typedef __attribute__((ext_vector_type(4))) float f32x4;

#define MFMA(a, b, c) __builtin_amdgcn_mfma_f32_16x16x32_bf16((a), (b), (c), 0, 0, 0)

// lgkm-only barrier: LDS sync without draining vmcnt (global ops stay in flight).
#define LGKM_BARRIER()                                      \
  do {                                                      \
    __builtin_amdgcn_sched_barrier(0);                      \
    asm volatile("s_waitcnt lgkmcnt(0)" ::: "memory");      \
    __builtin_amdgcn_s_barrier();                           \
    asm volatile("" ::: "memory");                          \
    __builtin_amdgcn_sched_barrier(0);                      \
  } while (0)

// Swizzled short-index into a [16][64]-short tile: byte ^= (row&7)<<4.
static __device__ __forceinline__ int swz(int row, int colshort) {
  return row * 64 + ((((colshort) << 1) ^ ((row & 7) << 4)) >> 1);
}

static __device__ __forceinline__ unsigned pk2(float a, float b) {
  __hip_bfloat162 t = __float22bfloat162_rn(make_float2(a, b));  // v_cvt_pk_bf16_f32
  unsigned r;
  __builtin_memcpy(&r, &t, sizeof(r));
  return r;
}
static __device__ __forceinline__ void pack4(f32x4 v, uint2 &H, uint2 &L) {
  H.x = pk2(v[0], v[1]);
  H.y = pk2(v[2], v[3]);
  float l0 = v[0] - __uint_as_float(H.x << 16);
  float l1 = v[1] - __uint_as_float(H.x & 0xffff0000u);
  float l2 = v[2] - __uint_as_float(H.y << 16);
  float l3 = v[3] - __uint_as_float(H.y & 0xffff0000u);
  L.x = pk2(l0, l1);
  L.y = pk2(l2, l3);
}
static __device__ __forceinline__ float sigm(float x) {
  return __builtin_amdgcn_rcpf(1.0f + __expf(-x));
}
static __device__ __forceinline__ float tanh_(float x) {
  return 2.0f * __builtin_amdgcn_rcpf(1.0f + __expf(-2.0f * x)) - 1.0f;
}
static __device__ __forceinline__ void split8(f32x4 a, f32x4 b, short8 &hi, short8 &lo) {
  uint2 H, L;
  pack4(a, H, L);
  hi[0] = (short)(H.x & 0xffff); hi[1] = (short)(H.x >> 16);
  hi[2] = (short)(H.y & 0xffff); hi[3] = (short)(H.y >> 16);
  lo[0] = (short)(L.x & 0xffff); lo[1] = (short)(L.x >> 16);
  lo[2] = (short)(L.y & 0xffff); lo[3] = (short)(L.y >> 16);
  pack4(b, H, L);
  hi[4] = (short)(H.x & 0xffff); hi[5] = (short)(H.x >> 16);
  hi[6] = (short)(H.y & 0xffff); hi[7] = (short)(H.y >> 16);
  lo[4] = (short)(L.x & 0xffff); lo[5] = (short)(L.x >> 16);
  lo[6] = (short)(L.y & 0xffff); lo[7] = (short)(L.y >> 16);
}

// 18 MFMAs: 3-term hi/lo input GEMM.
#define GI_X18(dR, dZ, dN, XH, XL)                   \
  _Pragma("unroll")                                  \
  for (int kc = 0; kc < 2; ++kc) {                   \
    dR = MFMA(wiH[0][kc], XH[kc], dR);               \
    dR = MFMA(wiH[0][kc], XL[kc], dR);               \
    dR = MFMA(wiL[0][kc], XH[kc], dR);               \
    dZ = MFMA(wiH[1][kc], XH[kc], dZ);               \
    dZ = MFMA(wiH[1][kc], XL[kc], dZ);               \
    dZ = MFMA(wiL[1][kc], XH[kc], dZ);               \
    dN = MFMA(wiH[2][kc], XH[kc], dN);               \
    dN = MFMA(wiH[2][kc], XL[kc], dN);               \
    dN = MFMA(wiL[2][kc], XH[kc], dN);               \
  }

// 12 MFMAs: 2-term (bf16 input) GEMM.
#define GI_X12(dR, dZ, dN, XB)                       \
  _Pragma("unroll")                                  \
  for (int kc = 0; kc < 2; ++kc) {                   \
    dR = MFMA(wiH[0][kc], XB[kc], dR);               \
    dR = MFMA(wiL[0][kc], XB[kc], dR);               \
    dZ = MFMA(wiH[1][kc], XB[kc], dZ);               \
    dZ = MFMA(wiL[1][kc], XB[kc], dZ);               \
    dN = MFMA(wiH[2][kc], XB[kc], dN);               \
    dN = MFMA(wiL[2][kc], XB[kc], dN);               \
  }

// 18 MFMAs: hidden GEMM; R/Z accumulate into gi values, N into aNh.
#define GH18(dR, dZ, dNh)                            \
  _Pragma("unroll")                                  \
  for (int kc = 0; kc < 2; ++kc) {                   \
    dR  = MFMA(whH[0][kc], hH[kc], dR);              \
    dR  = MFMA(whH[0][kc], hL[kc], dR);              \
    dR  = MFMA(whL[0][kc], hH[kc], dR);              \
    dZ  = MFMA(whH[1][kc], hH[kc], dZ);              \
    dZ  = MFMA(whH[1][kc], hL[kc], dZ);              \
    dZ  = MFMA(whL[1][kc], hH[kc], dZ);              \
    dNh = MFMA(whH[2][kc], hH[kc], dNh);             \
    dNh = MFMA(whH[2][kc], hL[kc], dNh);             \
    dNh = MFMA(whL[2][kc], hH[kc], dNh);             \
  }

// ---------------------------------------------------------------------------
// GRU + fused attention scores. 256 blocks x 512 thr (8 waves), 16 batch/blk.
// C layout (m89): col=lane&15 (=b), row=(lane>>4)*4+reg (=j).
// ---------------------------------------------------------------------------
__global__ __launch_bounds__(512, 1)
void gru_fwd(const float* __restrict__ x, const float* __restrict__ pq,
             const int* __restrict__ lengths,
             const float* __restrict__ Wih, const float* __restrict__ Whh,
             const float* __restrict__ bih, const float* __restrict__ bhh,
             unsigned short* __restrict__ outbf,   // [T][B][64] bf16
             float* __restrict__ scores)           // [B][T] fp32
{
  __shared__ alignas(16) unsigned short hbH[2][1024], hbL[2][1024];
  __shared__ alignas(16) unsigned short xbH[2][1024], xbL[2][1024];
  __shared__ alignas(16) f32x4 gilds[2][3][256];   // [buf][gate][jw*64+lane]
  __shared__ float slds[2][4][16];

  const int tid  = threadIdx.x;
  const int w    = tid >> 6;
  const int lane = tid & 63;
  const int c    = lane & 15;        // batch col / A row
  const int g    = lane >> 4;        // k-octet / C row group
  const int jw   = w & 3;
  const int jh   = jw * 16;
  const bool helper = (w >= 4);
  const int b_g  = blockIdx.x * BT + c;
  const int gl   = jw * 64 + lane;   // gilds index

  // helper x-staging map: 256 helper threads cover 16 b x 64 d, 4 floats each
  const int hp   = tid & 255;
  const int pb   = hp >> 4;
  const int pd   = 4 * (hp & 15);
  const int pb_g = blockIdx.x * BT + pb;

  for (int i = tid; i < 1024; i += 512) { hbH[0][i] = 0; hbL[0][i] = 0; }

  short8 wiH[3][2], wiL[3][2];   // helper-only
  short8 whH[3][2], whL[3][2];   // critical-only
  f32x4 bR, bZ, bNi, bNh;
  f32x4 pqv;
  const int len = lengths[b_g];

  if (helper) {
    // stage x(0), x(1)
#pragma unroll
    for (int t0 = 0; t0 < 2; ++t0) {
      f32x4 xf = *(const f32x4*)(x + (size_t)pb_g * Tq * 64 + t0 * 64 + pd);
      uint2 H, L; pack4(xf, H, L);
      const int si = swz(pb, pd);
      *(uint2*)&xbH[t0][si] = H;
      *(uint2*)&xbL[t0][si] = L;
    }
#pragma unroll
    for (int gt = 0; gt < 3; ++gt)
#pragma unroll
      for (int kc = 0; kc < 2; ++kc) {
        const float* p = Wih + (size_t)(gt * 64 + jh + c) * 64 + kc * 32 + g * 8;
        split8(*(const f32x4*)p, *(const f32x4*)(p + 4), wiH[gt][kc], wiL[gt][kc]);
      }
    f32x4 bi0 = *(const f32x4*)(bih + 0 * 64 + jh + 4 * g);
    f32x4 bh0 = *(const f32x4*)(bhh + 0 * 64 + jh + 4 * g);
    f32x4 bi1 = *(const f32x4*)(bih + 1 * 64 + jh + 4 * g);
    f32x4 bh1 = *(const f32x4*)(bhh + 1 * 64 + jh + 4 * g);
    bR = bi0 + bh0; bZ = bi1 + bh1;
    bNi = *(const f32x4*)(bih + 2 * 64 + jh + 4 * g);
  } else {
#pragma unroll
    for (int gt = 0; gt < 3; ++gt)
#pragma unroll
      for (int kc = 0; kc < 2; ++kc) {
        const float* q = Whh + (size_t)(gt * 64 + jh + c) * 64 + kc * 32 + g * 8;
        split8(*(const f32x4*)q, *(const f32x4*)(q + 4), whH[gt][kc], whL[gt][kc]);
      }
    bNh = *(const f32x4*)(bhh + 2 * 64 + jh + 4 * g);
    pqv = *(const f32x4*)(pq + (size_t)b_g * 64 + jh + 4 * g);
  }

  __syncthreads();

  if (helper) {  // gi(0) -> gilds[0]
    short8 xH[2], xL[2];
#pragma unroll
    for (int kc = 0; kc < 2; ++kc) {
      const int si = swz(c, kc * 32 + g * 8);
      xH[kc] = *(const short8*)&xbH[0][si];
      xL[kc] = *(const short8*)&xbL[0][si];
    }
    f32x4 nR = bR, nZ = bZ, nN = bNi;
    GI_X18(nR, nZ, nN, xH, xL);
    gilds[0][0][gl] = nR;
    gilds[0][1][gl] = nZ;
    gilds[0][2][gl] = nN;
  }
  f32x4 hreg = {0.f, 0.f, 0.f, 0.f};

  __syncthreads();

  for (int t = 0; t < Tq; ++t) {
    const int cur = t & 1, nxt = cur ^ 1;

    if (!helper) {
      // ---- critical: h-recurrence ----
      short8 hH[2], hL[2];
#pragma unroll
      for (int kc = 0; kc < 2; ++kc) {
        const int si = swz(c, kc * 32 + g * 8);
        hH[kc] = *(const short8*)&hbH[cur][si];
        hL[kc] = *(const short8*)&hbL[cur][si];
      }
      f32x4 aR  = gilds[cur][0][gl];
      f32x4 aZ  = gilds[cur][1][gl];
      f32x4 aNi = gilds[cur][2][gl];
      f32x4 aNh = bNh;
      GH18(aR, aZ, aNh);

      const bool valid = t < len;
      f32x4 outv;
#pragma unroll
      for (int r = 0; r < 4; ++r) {
        float rr = sigm(aR[r]);
        float zz = sigm(aZ[r]);
        float nn = tanh_(aNi[r] + rr * aNh[r]);
        float hn = (1.f - zz) * nn + zz * hreg[r];
        hreg[r] = valid ? hn : hreg[r];
        outv[r] = valid ? hn : 0.f;
      }

      uint2 H, L;
      pack4(hreg, H, L);
      {
        const int si = swz(c, jh + 4 * g);
        *(uint2*)&hbH[nxt][si] = H;
        *(uint2*)&hbL[nxt][si] = L;
      }

      float sp = outv[0] * pqv[0] + outv[1] * pqv[1] + outv[2] * pqv[2] + outv[3] * pqv[3];
      sp += __shfl_xor(sp, 16);
      sp += __shfl_xor(sp, 32);
      if (lane < 16) slds[cur][jw][lane] = sp;

      // out = bf16(masked h) (H when valid else 0)
      uint2 O;
      O.x = valid ? H.x : 0u;
      O.y = valid ? H.y : 0u;
      *(uint2*)(outbf + (size_t)t * Bq * 64 + (size_t)b_g * 64 + jh + 4 * g) = O;
    } else {
      // ---- helper: x pipeline + gi(t+1) + score finalize ----
      f32x4 xf = {0.f, 0.f, 0.f, 0.f};
      if (t + 2 < Tq)
        xf = *(const f32x4*)(x + (size_t)pb_g * Tq * 64 + (size_t)(t + 2) * 64 + pd);

      if (t + 1 < Tq) {
        short8 xH[2], xL[2];
#pragma unroll
        for (int kc = 0; kc < 2; ++kc) {
          const int si = swz(c, kc * 32 + g * 8);
          xH[kc] = *(const short8*)&xbH[nxt][si];
          xL[kc] = *(const short8*)&xbL[nxt][si];
        }
        f32x4 nR = bR, nZ = bZ, nN = bNi;
        GI_X18(nR, nZ, nN, xH, xL);
        gilds[nxt][0][gl] = nR;
        gilds[nxt][1][gl] = nZ;
        gilds[nxt][2][gl] = nN;
      }

      if (t + 2 < Tq) {
        uint2 H, L; pack4(xf, H, L);
        const int si = swz(pb, pd);
        *(uint2*)&xbH[cur][si] = H;
        *(uint2*)&xbL[cur][si] = L;
      }

      if (t > 0 && w == 4 && lane < 16) {
        float s = slds[nxt][0][lane] + slds[nxt][1][lane] +
                  slds[nxt][2][lane] + slds[nxt][3][lane];
        scores[(size_t)(blockIdx.x * BT + lane) * Tq + (t - 1)] = s;
      }
    }

    LGKM_BARRIER();
  }

  if (w == 4 && lane < 16) {
    const int pb2 = (Tq - 1) & 1;
    float s = slds[pb2][0][lane] + slds[pb2][1][lane] +
              slds[pb2][2][lane] + slds[pb2][3][lane];
    scores[(size_t)(blockIdx.x * BT + lane) * Tq + (Tq - 1)] = s;
  }
}

// ---------------------------------------------------------------------------
// Row softmax over scores (B rows of T=200). Wave per row.
// ---------------------------------------------------------------------------
__global__ __launch_bounds__(256)
void softmax_att(const float* __restrict__ scores, float* __restrict__ att)
{
  const int w = threadIdx.x >> 6, lane = threadIdx.x & 63;
  const int row = blockIdx.x * 4 + w;
  const float* s = scores + (size_t)row * Tq;
  float v0 = s[lane], v1 = s[lane + 64], v2 = s[lane + 128];
  float v3 = (lane < Tq - 192) ? s[lane + 192] : -1e30f;
  float m = fmaxf(fmaxf(v0, v1), fmaxf(v2, v3));
#pragma unroll
  for (int off = 32; off >= 1; off >>= 1) m = fmaxf(m, __shfl_xor(m, off));
  float e0 = __expf(v0 - m), e1 = __expf(v1 - m), e2 = __expf(v2 - m);
  float e3 = (lane < Tq - 192) ? __expf(v3 - m) : 0.f;
  float sum = e0 + e1 + e2 + e3;
#pragma unroll
  for (int off = 32; off >= 1; off >>= 1) sum += __shfl_xor(sum, off);
  float inv = 1.f / sum;
  float* a = att + (size_t)row * Tq;
  a[lane] = e0 * inv;
  a[lane + 64] = e1 * inv;
  a[lane + 128] = e2 * inv;
  if (lane < Tq - 192) a[lane + 192] = e3 * inv;
}

// ---------------------------------------------------------------------------
// AUGRU, wave-specialized. Helpers read bf16 `out` frags from global (full
// step of prefetch) and hand gi to criticals via gilds.
// ---------------------------------------------------------------------------
__global__ __launch_bounds__(512, 1)
void augru_fwd(const unsigned short* __restrict__ outbf, const float* __restrict__ att,
               const int* __restrict__ lengths,
               const float* __restrict__ Wih, const float* __restrict__ Whh,
               const float* __restrict__ bih, const float* __restrict__ bhh,
               float* __restrict__ hout)
{
  __shared__ alignas(16) unsigned short hbH[2][1024], hbL[2][1024];
  __shared__ alignas(16) f32x4 gilds[2][3][256];
  __shared__ float att_lds[16][201];

  const int tid  = threadIdx.x;
  const int w    = tid >> 6;
  const int lane = tid & 63;
  const int c    = lane & 15;
  const int g    = lane >> 4;
  const int jw   = w & 3;
  const int jh   = jw * 16;
  const bool helper = (w >= 4);
  const int b_g  = blockIdx.x * BT + c;
  const int gl   = jw * 64 + lane;

  for (int i = tid; i < 1024; i += 512) { hbH[0][i] = 0; hbL[0][i] = 0; }
  for (int i = tid; i < BT * Tq; i += 512)
    att_lds[i / Tq][i % Tq] = att[(size_t)blockIdx.x * BT * Tq + i];

  short8 wiH[3][2], wiL[3][2];
  short8 whH[3][2], whL[3][2];
  f32x4 bR, bZ, bNi, bNh;
  const int len = lengths[b_g];

  if (helper) {
#pragma unroll
    for (int gt = 0; gt < 3; ++gt)
#pragma unroll
      for (int kc = 0; kc < 2; ++kc) {
        const float* p = Wih + (size_t)(gt * 64 + jh + c) * 64 + kc * 32 + g * 8;
        split8(*(const f32x4*)p, *(const f32x4*)(p + 4), wiH[gt][kc], wiL[gt][kc]);
      }
    f32x4 bi0 = *(const f32x4*)(bih + 0 * 64 + jh + 4 * g);
    f32x4 bh0 = *(const f32x4*)(bhh + 0 * 64 + jh + 4 * g);
    f32x4 bi1 = *(const f32x4*)(bih + 1 * 64 + jh + 4 * g);
    f32x4 bh1 = *(const f32x4*)(bhh + 1 * 64 + jh + 4 * g);
    bR = bi0 + bh0; bZ = bi1 + bh1;
    bNi = *(const f32x4*)(bih + 2 * 64 + jh + 4 * g);
  } else {
#pragma unroll
    for (int gt = 0; gt < 3; ++gt)
#pragma unroll
      for (int kc = 0; kc < 2; ++kc) {
        const float* q = Whh + (size_t)(gt * 64 + jh + c) * 64 + kc * 32 + g * 8;
        split8(*(const f32x4*)q, *(const f32x4*)(q + 4), whH[gt][kc], whL[gt][kc]);
      }
    bNh = *(const f32x4*)(bhh + 2 * 64 + jh + 4 * g);
  }

  __syncthreads();

  short8 xnA, xnB;  // helper: out(t+1) frags, loaded one step ahead
  if (helper) {
    // gi(0) from out(0)
    short8 x0[2];
#pragma unroll
    for (int kc = 0; kc < 2; ++kc)
      x0[kc] = *(const short8*)(outbf + (size_t)b_g * 64 + kc * 32 + g * 8);
    f32x4 nR = bR, nZ = bZ, nN = bNi;
    GI_X12(nR, nZ, nN, x0);
    gilds[0][0][gl] = nR;
    gilds[0][1][gl] = nZ;
    gilds[0][2][gl] = nN;
    // prefetch out(1)
    xnA = *(const short8*)(outbf + (size_t)1 * Bq * 64 + (size_t)b_g * 64 + 0 * 32 + g * 8);
    xnB = *(const short8*)(outbf + (size_t)1 * Bq * 64 + (size_t)b_g * 64 + 1 * 32 + g * 8);
  }
  f32x4 hreg = {0.f, 0.f, 0.f, 0.f};

  __syncthreads();

  for (int t = 0; t < Tq; ++t) {
    const int cur = t & 1, nxt = cur ^ 1;

    if (!helper) {
      short8 hH[2], hL[2];
#pragma unroll
      for (int kc = 0; kc < 2; ++kc) {
        const int si = swz(c, kc * 32 + g * 8);
        hH[kc] = *(const short8*)&hbH[cur][si];
        hL[kc] = *(const short8*)&hbL[cur][si];
      }
      f32x4 aR  = gilds[cur][0][gl];
      f32x4 aZ  = gilds[cur][1][gl];
      f32x4 aNi = gilds[cur][2][gl];
      f32x4 aNh = bNh;
      GH18(aR, aZ, aNh);

      const float a_t = att_lds[c][t];
      const bool valid = t < len;
#pragma unroll
      for (int r = 0; r < 4; ++r) {
        float rr = sigm(aR[r]);
        float uu = a_t * sigm(aZ[r]);
        float nn = tanh_(aNi[r] + rr * aNh[r]);
        float hn = (1.f - uu) * hreg[r] + uu * nn;   // AUGRU blend orientation
        hreg[r] = valid ? hn : hreg[r];
      }

      uint2 H, L;
      pack4(hreg, H, L);
      const int si = swz(c, jh + 4 * g);
      *(uint2*)&hbH[nxt][si] = H;
      *(uint2*)&hbL[nxt][si] = L;
    } else {
      if (t + 1 < Tq) {
        short8 xb2[2];
        xb2[0] = xnA; xb2[1] = xnB;
        f32x4 nR = bR, nZ = bZ, nN = bNi;
        GI_X12(nR, nZ, nN, xb2);
        gilds[nxt][0][gl] = nR;
        gilds[nxt][1][gl] = nZ;
        gilds[nxt][2][gl] = nN;
      }
      if (t + 2 < Tq) {
        xnA = *(const short8*)(outbf + (size_t)(t + 2) * Bq * 64 +
                               (size_t)b_g * 64 + 0 * 32 + g * 8);
        xnB = *(const short8*)(outbf + (size_t)(t + 2) * Bq * 64 +
                               (size_t)b_g * 64 + 1 * 32 + g * 8);
      }
    }

    LGKM_BARRIER();
  }

  if (!helper)
    *(f32x4*)(hout + (size_t)b_g * 64 + jh + 4 * g) = hreg;
}

// ---------------------------------------------------------------------------
extern "C" void kernel_launch(void* const* d_in, const int* in_sizes, int n_in,
                              void* d_out, int out_size, void* d_ws, size_t ws_size,
                              hipStream_t stream)
{
  const float* x       = (const float*)d_in[0];
  const float* pq      = (const float*)d_in[1];
  const int*   lengths = (const int*)d_in[2];
  const float* Wih     = (const float*)d_in[3];
  const float* Whh     = (const float*)d_in[4];
  const float* bih     = (const float*)d_in[5];
  const float* bhh     = (const float*)d_in[6];
  const float* aWih    = (const float*)d_in[7];
  const float* aWhh    = (const float*)d_in[8];
  const float* abih    = (const float*)d_in[9];
  const float* abhh    = (const float*)d_in[10];
  float* hout = (float*)d_out;

  // ws: out bf16 [T][B][64] (104.8 MB) | scores [B][T] | att [B][T]
  char* ws = (char*)d_ws;
  unsigned short* outbf = (unsigned short*)ws;
  float* scores = (float*)(ws + (size_t)Tq * Bq * 64 * 2);
  float* att    = scores + (size_t)Bq * Tq;

  gru_fwd<<<Bq / BT, 512, 0, stream>>>(x, pq, lengths, Wih, Whh, bih, bhh, outbf, scores);
  softmax_att<<<Bq / 4, 256, 0, stream>>>(scores, att);
  augru_fwd<<<Bq / BT, 512, 0, stream>>>(outbf, att, lengths, aWih, aWhh, abih, abhh, hout);
}